// Round 4
// baseline (477.629 us; speedup 1.0000x reference)
//
#include <hip/hip_runtime.h>

// Problem constants (fixed by reference setup_inputs)
#define BT    16384          // b*t = 4*4096
#define TSEQ  4096           // time steps per batch
#define DM    1024           // d_model
#define EXP   1024           // expanded
#define N1    2048           // 2*EXP
#define KDIM  1024           // GEMM K (both GEMMs)
#define NKT2  (KDIM / 32)    // 32 K-tiles of BK=32
#define EPSV  1e-8f

typedef __bf16 bf16x8 __attribute__((ext_vector_type(8)));
typedef float f32x16 __attribute__((ext_vector_type(16)));
typedef unsigned short u16x8 __attribute__((ext_vector_type(8)));

#define AS1CAST(p) ((__attribute__((address_space(1))) void*)(p))
#define AS3CAST(p) ((__attribute__((address_space(3))) void*)(p))

__device__ __forceinline__ unsigned short f2bf(float f) {
    unsigned int u = __float_as_uint(f);
    u += 0x7fffu + ((u >> 16) & 1u);
    return (unsigned short)(u >> 16);
}

// ---------------------------------------------------------------------------
// fp32 -> bf16 conversion for all three inputs + zero-init of
// ssq1[BT] + ssq2[BT] + cnt[64] (contiguous), all in ONE launch.
__global__ __launch_bounds__(256) void k_f2bf3(const float* __restrict__ i0, unsigned short* __restrict__ o0, int n0,
                                               const float* __restrict__ i1, unsigned short* __restrict__ o1, int n1,
                                               const float* __restrict__ i2, unsigned short* __restrict__ o2, int n2,
                                               float* __restrict__ ssq) {
    int i = blockIdx.x * 256 + threadIdx.x;
    const float* in; unsigned short* out;
    if (i < n0)                { in = i0; out = o0; }
    else if (i < n0 + n1)      { in = i1; out = o1; i -= n0; }
    else if (i < n0 + n1 + n2) { in = i2; out = o2; i -= n0 + n1; }
    else {
        i -= n0 + n1 + n2;
        if (i < (2 * BT + 64) / 4) ((float4*)ssq)[i] = make_float4(0.f, 0.f, 0.f, 0.f);
        return;
    }
    float4 v = ((const float4*)in)[i];
    ushort4 o;
    o.x = f2bf(v.x); o.y = f2bf(v.y); o.z = f2bf(v.z); o.w = f2bf(v.w);
    ((ushort4*)out)[i] = o;
}

// ---------------------------------------------------------------------------
// bf16 GEMM (round-1 structure, best measured: 82.4 us / 832 TF):
// C[m,n] = sum_k A[m,k]*B[n,k] + bias[n].
// Block tile 256(M)x128(N), 256 thr = 4 waves partitioning M; wave tile
// 64x128 = 2x4 grid of 32x32x16 MFMA (128 AGPR).
// BK=32, THREE LDS buffers (24 KB each, 72 KB), counted-vmcnt pipeline:
// ONE raw s_barrier per K-tile, vmcnt(6) keeps stage(kt+1)/stage(kt+2)
// in flight across the barrier. Quarter swizzle phys=(q+(row>>2))&3 on
// both stage-source and fragment reads (measured 0 bank conflicts).
// T5 setprio around the MFMA cluster. XCD swizzle on blockIdx: the 8
// blocks sharing an A-panel (same mt, all nt) are 8 apart in linear ID
// -> SAME XCD under round-robin dispatch (L2-local A reuse, and the
// k_gemm_out finisher reads its row-group from its own XCD's L2).
// Epilogue: C-store + per-row sum-sq -> one atomicAdd per row.
template <int BF16_OUT, int NT>
__device__ __forceinline__ void gemm_body(const unsigned short* __restrict__ A,
                                          const unsigned short* __restrict__ Bw,
                                          const float* __restrict__ bias,
                                          unsigned short* __restrict__ Cb,
                                          float* __restrict__ Cf,
                                          float* __restrict__ ssq,
                                          int N) {
    __shared__ __align__(16) char smem[73728];     // 3 x (16 KB A + 8 KB B)

    const int tid  = threadIdx.x;
    const int lane = tid & 63;
    const int w    = tid >> 6;
    const int ln   = lane & 31;
    const int hi   = lane >> 5;

    const int L   = blockIdx.x;
    const int mt  = ((L >> 3) / NT) * 8 + (L & 7);
    const int nt  = (L >> 3) & (NT - 1);
    const int row0 = mt * 256, col0 = nt * 128;

    const int rA = tid >> 2;
    const int qS = ((tid & 3) - (tid >> 4)) & 3;
    const unsigned short* aSrc = A  + (size_t)(row0 + rA) * KDIM + qS * 8;
    const unsigned short* bSrc = Bw + (size_t)(col0 + rA) * KDIM + qS * 8;

    f32x16 acc[2][4] = {};

    auto stage = [&](int kt, unsigned short* sA, unsigned short* sB) {
#pragma unroll
        for (int b = 0; b < 4; ++b)
            __builtin_amdgcn_global_load_lds(AS1CAST(aSrc + (size_t)b * 64 * KDIM + kt * 32),
                                             AS3CAST(&sA[(b * 256 + w * 64) * 8]), 16, 0, 0);
#pragma unroll
        for (int b = 0; b < 2; ++b)
            __builtin_amdgcn_global_load_lds(AS1CAST(bSrc + (size_t)b * 64 * KDIM + kt * 32),
                                             AS3CAST(&sB[(b * 256 + w * 64) * 8]), 16, 0, 0);
    };
    auto compute = [&](const unsigned short* sA, const unsigned short* sB) {
#pragma unroll
        for (int ks = 0; ks < 2; ++ks) {
            const int sw = ((ks * 2 + hi + (ln >> 2)) & 3) * 8;   // swizzled quarter
            bf16x8 aF[2], bF[4];
#pragma unroll
            for (int i = 0; i < 2; ++i)
                aF[i] = *(const bf16x8*)&sA[(w * 64 + i * 32 + ln) * 32 + sw];
#pragma unroll
            for (int j = 0; j < 4; ++j)
                bF[j] = *(const bf16x8*)&sB[(j * 32 + ln) * 32 + sw];
            __builtin_amdgcn_s_setprio(1);
#pragma unroll
            for (int i = 0; i < 2; ++i)
#pragma unroll
                for (int j = 0; j < 4; ++j)
                    acc[i][j] = __builtin_amdgcn_mfma_f32_32x32x16_bf16(
                        aF[i], bF[j], acc[i][j], 0, 0, 0);
            __builtin_amdgcn_s_setprio(0);
        }
    };

    unsigned short* A0 = (unsigned short*)smem;
    unsigned short* B0 = (unsigned short*)(smem + 16384);
    unsigned short* A1 = (unsigned short*)(smem + 24576);
    unsigned short* B1 = (unsigned short*)(smem + 40960);
    unsigned short* A2 = (unsigned short*)(smem + 49152);
    unsigned short* B2 = (unsigned short*)(smem + 65536);

    stage(0, A0, B0);
    stage(1, A1, B1);
    for (int kt = 0; kt < NKT2 - 1; ++kt) {
        asm volatile("s_waitcnt vmcnt(6)" ::: "memory");
        __builtin_amdgcn_s_barrier();
        if (kt + 2 < NKT2) stage(kt + 2, A2, B2);   // issue-early; hides behind MFMA
        compute(A0, B0);
        unsigned short* tA = A0; A0 = A1; A1 = A2; A2 = tA;
        unsigned short* tB = B0; B0 = B1; B1 = B2; B2 = tB;
    }
    asm volatile("s_waitcnt vmcnt(0)" ::: "memory");  // peeled last tile
    __builtin_amdgcn_s_barrier();
    compute(A0, B0);

    // ---- epilogue ----
    // C/D: col = lane&31 (+j*32), row = (reg&3) + 8*(reg>>2) + 4*hi
    const int c0 = col0 + ln;
    float bs[4];
#pragma unroll
    for (int j = 0; j < 4; ++j) bs[j] = bias[c0 + j * 32];

    __syncthreads();                           // done with LDS K-buffers
    float* scr = (float*)smem;                 // [256][33] = 33.8 KB

#pragma unroll
    for (int i = 0; i < 2; ++i) {
        const int lr0 = w * 64 + i * 32 + 4 * hi;   // local row base
#pragma unroll
        for (int reg = 0; reg < 16; ++reg) {
            const int lr = lr0 + (reg & 3) + 8 * (reg >> 2);
            const int gm = row0 + lr;
            float v[4]; float p = 0.f;
#pragma unroll
            for (int j = 0; j < 4; ++j) {
                v[j] = acc[i][j][reg] + bs[j];
                p += v[j] * v[j];
            }
            scr[lr * 33 + ln] = p;             // conflict-free: banks (lr+ln)%32
            size_t base = (size_t)gm * N + c0;
#pragma unroll
            for (int j = 0; j < 4; ++j) {
                if (BF16_OUT) Cb[base + j * 32] = f2bf(v[j]);
                else          Cf[base + j * 32] = v[j];
            }
        }
    }
    __syncthreads();
    float s = 0.f;
#pragma unroll
    for (int c = 0; c < 32; ++c) s += scr[tid * 33 + c];
    atomicAdd(&ssq[row0 + tid], s);
}

__global__ __launch_bounds__(256, 2) void k_gemm_in(const unsigned short* __restrict__ A,
                                                    const unsigned short* __restrict__ Bw,
                                                    const float* __restrict__ bias,
                                                    unsigned short* __restrict__ Cb,
                                                    float* __restrict__ ssq) {
    gemm_body<1, 16>(A, Bw, bias, Cb, nullptr, ssq, N1);
}

// ---------------------------------------------------------------------------
// Second GEMM (fp32 C to d_out) + FUSED output RMSNorm via last-block
// finisher: after the C-store + ssq2 atomics, each block does
// release-fence + atomicAdd(cnt[mt]); the 8th (last) block of the
// row-group acquires and rescales the 256x1024 fp32 row-group in place
// (1 MB RW, L2-local: all 8 writer blocks share this XCD by the grid
// swizzle). Replaces the separate 128 MB k_outnorm pass + one launch.
// No dispatch-order assumption: only "counter reached 8" (G16-safe,
// device-scope atomics + __threadfence).
__global__ __launch_bounds__(256, 2) void k_gemm_out(const unsigned short* __restrict__ A,
                                                     const unsigned short* __restrict__ Bw,
                                                     const float* __restrict__ bias,
                                                     float* __restrict__ Cf,
                                                     float* __restrict__ ssq,
                                                     const float* __restrict__ onw,
                                                     int* __restrict__ cnt) {
    gemm_body<0, 8>(A, Bw, bias, nullptr, Cf, ssq, DM);

    const int L   = blockIdx.x;
    const int mt  = ((L >> 3) / 8) * 8 + (L & 7);
    const int row0 = mt * 256;

    __shared__ int done;
    __shared__ float rsbuf[256];

    __threadfence();                               // release: C rows + ssq atomics visible
    if (threadIdx.x == 0) done = atomicAdd(&cnt[mt], 1);
    __syncthreads();
    if (done != 7) return;                         // not the last of the 8 N-tiles

    __threadfence();                               // acquire side
    rsbuf[threadIdx.x] = rsqrtf(ssq[row0 + threadIdx.x] * (1.0f / DM) + EPSV);
    __syncthreads();

    const float4 wv = ((const float4*)onw)[threadIdx.x];   // DM/4 = 256 float4
    float4* Of = (float4*)Cf;
#pragma unroll 4
    for (int r = 0; r < 256; ++r) {
        const float rs = rsbuf[r];
        const size_t idx = (size_t)(row0 + r) * 256 + threadIdx.x;
        float4 v = Of[idx];
        v.x *= rs * wv.x; v.y *= rs * wv.y; v.z *= rs * wv.z; v.w *= rs * wv.w;
        Of[idx] = v;
    }
}

// ---------------------------------------------------------------------------
// RMSNorm(z) -> split x|v -> depthwise conv(K=3, same, per-batch) -> gate
// 2 tokens / block; 128 threads/token; 8 channels/thread.
// XCD-chunked token mapping: contiguous 2048-token chunk per XCD so the
// x-rows re-read by tokens t-1/t/t+1 hit the local L2 (default
// round-robin spreads adjacent tokens across XCDs -> 3 L2 copies).
// Chunks (2048 tokens) never straddle batch boundaries (4096).
__global__ __launch_bounds__(256) void k_conv_gate(const unsigned short* __restrict__ z,
                                                   const float* __restrict__ ssq1,
                                                   const float* __restrict__ inw,
                                                   const float* __restrict__ cw,
                                                   const float* __restrict__ cb,
                                                   unsigned short* __restrict__ g) {
    const int L   = blockIdx.x;                       // 8192 blocks
    const int blk = (L & 7) * 1024 + (L >> 3);        // bijective chunk map
    const int tok = blk * 2 + (threadIdx.x >> 7);
    const int e8  = (threadIdx.x & 127) * 8;
    const int t   = tok & (TSEQ - 1);

    const float rs0 = rsqrtf(ssq1[tok] * (1.0f / N1) + EPSV);
    const int tm = (t > 0) ? tok - 1 : tok;
    const int tp = (t < TSEQ - 1) ? tok + 1 : tok;
    const float rsm = (t > 0) ? rsqrtf(ssq1[tm] * (1.0f / N1) + EPSV) : 0.0f;
    const float rsp = (t < TSEQ - 1) ? rsqrtf(ssq1[tp] * (1.0f / N1) + EPSV) : 0.0f;

    bf16x8 xm = *(const bf16x8*)(z + (size_t)tm * N1 + e8);
    bf16x8 x0 = *(const bf16x8*)(z + (size_t)tok * N1 + e8);
    bf16x8 xp = *(const bf16x8*)(z + (size_t)tp * N1 + e8);
    bf16x8 vv = *(const bf16x8*)(z + (size_t)tok * N1 + EXP + e8);

    u16x8 ov;
#pragma unroll
    for (int p = 0; p < 8; ++p) {
        const int e = e8 + p;
        const float we  = inw[e];
        const float wvv = inw[EXP + e];
        const float w0 = cw[e * 3], w1 = cw[e * 3 + 1], w2 = cw[e * 3 + 2];
        float y = w0 * ((float)xm[p] * rsm * we)
                + w1 * ((float)x0[p] * rs0 * we)
                + w2 * ((float)xp[p] * rsp * we)
                + cb[e];
        float vn = (float)vv[p] * rs0 * wvv;
        ov[p] = f2bf(vn * y);
    }
    *(u16x8*)(g + (size_t)tok * EXP + e8) = ov;
}

// ---------------------------------------------------------------------------
extern "C" void kernel_launch(void* const* d_in, const int* in_sizes, int n_in,
                              void* d_out, int out_size, void* d_ws, size_t ws_size,
                              hipStream_t stream) {
    const float* u     = (const float*)d_in[0];
    const float* W_in  = (const float*)d_in[1];
    const float* b_in  = (const float*)d_in[2];
    const float* inw   = (const float*)d_in[3];
    const float* cw    = (const float*)d_in[4];
    const float* cb    = (const float*)d_in[5];
    const float* W_out = (const float*)d_in[6];
    const float* b_out = (const float*)d_in[7];
    const float* onw   = (const float*)d_in[8];
    float* out = (float*)d_out;

    char* ws = (char*)d_ws;
    unsigned short* u_bf    = (unsigned short*)ws; ws += (size_t)BT * DM * 2;     // 32 MB
    unsigned short* Win_bf  = (unsigned short*)ws; ws += (size_t)N1 * DM * 2;     //  4 MB
    unsigned short* Wout_bf = (unsigned short*)ws; ws += (size_t)DM * EXP * 2;    //  2 MB
    unsigned short* z_bf    = (unsigned short*)ws; ws += (size_t)BT * N1 * 2;     // 64 MB
    unsigned short* g_bf    = (unsigned short*)ws; ws += (size_t)BT * EXP * 2;    // 32 MB
    float* ssq1 = (float*)ws; ws += (size_t)BT * 4;
    float* ssq2 = (float*)ws; ws += (size_t)BT * 4;   // contiguous after ssq1
    int*   cnt  = (int*)ws;  ws += 64 * 4;            // contiguous after ssq2

    const int n0 = BT * DM / 4, n1c = N1 * DM / 4, n2c = DM * EXP / 4;
    const int ntot = n0 + n1c + n2c + (2 * BT + 64) / 4;
    k_f2bf3<<<(ntot + 255) / 256, 256, 0, stream>>>(u, u_bf, n0,
                                                    W_in, Win_bf, n1c,
                                                    W_out, Wout_bf, n2c,
                                                    ssq1);

    k_gemm_in<<<(BT / 256) * (N1 / 128), 256, 0, stream>>>(u_bf, Win_bf, b_in, z_bf, ssq1);

    k_conv_gate<<<BT / 2, 256, 0, stream>>>(z_bf, ssq1, inw, cw, cb, g_bf);

    k_gemm_out<<<(BT / 256) * (DM / 128), 256, 0, stream>>>(g_bf, Wout_bf, b_out, out, ssq2, onw, cnt);

    (void)in_sizes; (void)n_in; (void)out_size; (void)ws_size;
}

// Round 5
// 305.180 us; speedup vs baseline: 1.5651x; 1.5651x over previous
//
#include <hip/hip_runtime.h>

// Problem constants (fixed by reference setup_inputs)
#define BT    16384          // b*t = 4*4096
#define TSEQ  4096           // time steps per batch
#define DM    1024           // d_model
#define EXP   1024           // expanded
#define N1    2048           // 2*EXP
#define KDIM  1024           // GEMM K (both GEMMs)
#define NKT2  (KDIM / 32)    // 32 K-tiles of BK=32
#define EPSV  1e-8f

typedef __bf16 bf16x8 __attribute__((ext_vector_type(8)));
typedef float f32x16 __attribute__((ext_vector_type(16)));
typedef unsigned short u16x8 __attribute__((ext_vector_type(8)));

#define AS1CAST(p) ((__attribute__((address_space(1))) void*)(p))
#define AS3CAST(p) ((__attribute__((address_space(3))) void*)(p))

__device__ __forceinline__ unsigned short f2bf(float f) {
    unsigned int u = __float_as_uint(f);
    u += 0x7fffu + ((u >> 16) & 1u);
    return (unsigned short)(u >> 16);
}

// ---------------------------------------------------------------------------
// fp32 -> bf16 conversion for all three inputs + zero-init of ssq[2*BT],
// all in ONE launch (4 elems/thread).
__global__ __launch_bounds__(256) void k_f2bf3(const float* __restrict__ i0, unsigned short* __restrict__ o0, int n0,
                                               const float* __restrict__ i1, unsigned short* __restrict__ o1, int n1,
                                               const float* __restrict__ i2, unsigned short* __restrict__ o2, int n2,
                                               float* __restrict__ ssq) {
    int i = blockIdx.x * 256 + threadIdx.x;
    const float* in; unsigned short* out;
    if (i < n0)                { in = i0; out = o0; }
    else if (i < n0 + n1)      { in = i1; out = o1; i -= n0; }
    else if (i < n0 + n1 + n2) { in = i2; out = o2; i -= n0 + n1; }
    else {
        i -= n0 + n1 + n2;
        if (i < 2 * BT / 4) ((float4*)ssq)[i] = make_float4(0.f, 0.f, 0.f, 0.f);
        return;
    }
    float4 v = ((const float4*)in)[i];
    ushort4 o;
    o.x = f2bf(v.x); o.y = f2bf(v.y); o.z = f2bf(v.z); o.w = f2bf(v.w);
    ((ushort4*)out)[i] = o;
}

// ---------------------------------------------------------------------------
// bf16 GEMM (round-1 structure, best measured: 82.4 us / 832 TF):
// C[m,n] = sum_k A[m,k]*B[n,k] + bias[n].
// Block tile 256(M)x128(N), 256 thr = 4 waves partitioning M; wave tile
// 64x128 = 2x4 grid of 32x32x16 MFMA (128 AGPR).
// BK=32, THREE LDS buffers (24 KB each, 72 KB), counted-vmcnt pipeline:
// ONE raw s_barrier per K-tile, vmcnt(6) keeps stage(kt+1)/stage(kt+2)
// in flight across the barrier (never a full drain in the main loop).
// Quarter swizzle phys=(q+(row>>2))&3 on both stage-source and fragment
// reads (measured: SQ_LDS_BANK_CONFLICT 1.9e7 -> 0).
// T5 setprio around the MFMA cluster. XCD swizzle on blockIdx.
// NOTE (round-4 lesson): do NOT add device-scope fences/finishers here --
// __threadfence() costs a cross-XCD L2 writeback per block (gemm_out went
// 45 -> 229 us). Cross-block fusion is dead on this chip.
// Epilogue: C-store + per-row sum-sq -> one atomicAdd per row.
template <int BF16_OUT, int NT>
__device__ __forceinline__ void gemm_body(const unsigned short* __restrict__ A,
                                          const unsigned short* __restrict__ Bw,
                                          const float* __restrict__ bias,
                                          unsigned short* __restrict__ Cb,
                                          float* __restrict__ Cf,
                                          float* __restrict__ ssq,
                                          int N) {
    __shared__ __align__(16) char smem[73728];     // 3 x (16 KB A + 8 KB B)

    const int tid  = threadIdx.x;
    const int lane = tid & 63;
    const int w    = tid >> 6;
    const int ln   = lane & 31;
    const int hi   = lane >> 5;

    const int L   = blockIdx.x;
    const int mt  = ((L >> 3) / NT) * 8 + (L & 7);
    const int nt  = (L >> 3) & (NT - 1);
    const int row0 = mt * 256, col0 = nt * 128;

    const int rA = tid >> 2;
    const int qS = ((tid & 3) - (tid >> 4)) & 3;
    const unsigned short* aSrc = A  + (size_t)(row0 + rA) * KDIM + qS * 8;
    const unsigned short* bSrc = Bw + (size_t)(col0 + rA) * KDIM + qS * 8;

    f32x16 acc[2][4] = {};

    auto stage = [&](int kt, unsigned short* sA, unsigned short* sB) {
#pragma unroll
        for (int b = 0; b < 4; ++b)
            __builtin_amdgcn_global_load_lds(AS1CAST(aSrc + (size_t)b * 64 * KDIM + kt * 32),
                                             AS3CAST(&sA[(b * 256 + w * 64) * 8]), 16, 0, 0);
#pragma unroll
        for (int b = 0; b < 2; ++b)
            __builtin_amdgcn_global_load_lds(AS1CAST(bSrc + (size_t)b * 64 * KDIM + kt * 32),
                                             AS3CAST(&sB[(b * 256 + w * 64) * 8]), 16, 0, 0);
    };
    auto compute = [&](const unsigned short* sA, const unsigned short* sB) {
#pragma unroll
        for (int ks = 0; ks < 2; ++ks) {
            const int sw = ((ks * 2 + hi + (ln >> 2)) & 3) * 8;   // swizzled quarter
            bf16x8 aF[2], bF[4];
#pragma unroll
            for (int i = 0; i < 2; ++i)
                aF[i] = *(const bf16x8*)&sA[(w * 64 + i * 32 + ln) * 32 + sw];
#pragma unroll
            for (int j = 0; j < 4; ++j)
                bF[j] = *(const bf16x8*)&sB[(j * 32 + ln) * 32 + sw];
            __builtin_amdgcn_s_setprio(1);
#pragma unroll
            for (int i = 0; i < 2; ++i)
#pragma unroll
                for (int j = 0; j < 4; ++j)
                    acc[i][j] = __builtin_amdgcn_mfma_f32_32x32x16_bf16(
                        aF[i], bF[j], acc[i][j], 0, 0, 0);
            __builtin_amdgcn_s_setprio(0);
        }
    };

    unsigned short* A0 = (unsigned short*)smem;
    unsigned short* B0 = (unsigned short*)(smem + 16384);
    unsigned short* A1 = (unsigned short*)(smem + 24576);
    unsigned short* B1 = (unsigned short*)(smem + 40960);
    unsigned short* A2 = (unsigned short*)(smem + 49152);
    unsigned short* B2 = (unsigned short*)(smem + 65536);

    stage(0, A0, B0);
    stage(1, A1, B1);
    for (int kt = 0; kt < NKT2 - 1; ++kt) {
        asm volatile("s_waitcnt vmcnt(6)" ::: "memory");
        __builtin_amdgcn_s_barrier();
        if (kt + 2 < NKT2) stage(kt + 2, A2, B2);   // issue-early; hides behind MFMA
        compute(A0, B0);
        unsigned short* tA = A0; A0 = A1; A1 = A2; A2 = tA;
        unsigned short* tB = B0; B0 = B1; B1 = B2; B2 = tB;
    }
    asm volatile("s_waitcnt vmcnt(0)" ::: "memory");  // peeled last tile
    __builtin_amdgcn_s_barrier();
    compute(A0, B0);

    // ---- epilogue ----
    // C/D: col = lane&31 (+j*32), row = (reg&3) + 8*(reg>>2) + 4*hi
    const int c0 = col0 + ln;
    float bs[4];
#pragma unroll
    for (int j = 0; j < 4; ++j) bs[j] = bias[c0 + j * 32];

    __syncthreads();                           // done with LDS K-buffers
    float* scr = (float*)smem;                 // [256][33] = 33.8 KB

#pragma unroll
    for (int i = 0; i < 2; ++i) {
        const int lr0 = w * 64 + i * 32 + 4 * hi;   // local row base
#pragma unroll
        for (int reg = 0; reg < 16; ++reg) {
            const int lr = lr0 + (reg & 3) + 8 * (reg >> 2);
            const int gm = row0 + lr;
            float v[4]; float p = 0.f;
#pragma unroll
            for (int j = 0; j < 4; ++j) {
                v[j] = acc[i][j][reg] + bs[j];
                p += v[j] * v[j];
            }
            scr[lr * 33 + ln] = p;             // conflict-free: banks (lr+ln)%32
            size_t base = (size_t)gm * N + c0;
#pragma unroll
            for (int j = 0; j < 4; ++j) {
                if (BF16_OUT) Cb[base + j * 32] = f2bf(v[j]);
                else          Cf[base + j * 32] = v[j];
            }
        }
    }
    __syncthreads();
    float s = 0.f;
#pragma unroll
    for (int c = 0; c < 32; ++c) s += scr[tid * 33 + c];
    atomicAdd(&ssq[row0 + tid], s);
}

__global__ __launch_bounds__(256, 2) void k_gemm_in(const unsigned short* __restrict__ A,
                                                    const unsigned short* __restrict__ Bw,
                                                    const float* __restrict__ bias,
                                                    unsigned short* __restrict__ Cb,
                                                    float* __restrict__ ssq) {
    gemm_body<1, 16>(A, Bw, bias, Cb, nullptr, ssq, N1);
}

__global__ __launch_bounds__(256, 2) void k_gemm_out(const unsigned short* __restrict__ A,
                                                     const unsigned short* __restrict__ Bw,
                                                     const float* __restrict__ bias,
                                                     float* __restrict__ Cf,
                                                     float* __restrict__ ssq) {
    gemm_body<0, 8>(A, Bw, bias, nullptr, Cf, ssq, DM);
}

// ---------------------------------------------------------------------------
// RMSNorm(z) -> split x|v -> depthwise conv(K=3, same, per-batch) -> gate
// 2 tokens / block; 128 threads/token; 8 channels/thread.
// XCD-chunked token mapping (isolated from round 4 -- the safe half):
// contiguous 2048-token chunk per XCD so the x-rows re-read by tokens
// t-1/t/t+1 hit the local L2 (round-robin spreads adjacent tokens across
// XCDs -> 3 L2 copies). Bijective; chunks never straddle batch bounds.
__global__ __launch_bounds__(256) void k_conv_gate(const unsigned short* __restrict__ z,
                                                   const float* __restrict__ ssq1,
                                                   const float* __restrict__ inw,
                                                   const float* __restrict__ cw,
                                                   const float* __restrict__ cb,
                                                   unsigned short* __restrict__ g) {
    const int L   = blockIdx.x;                       // 8192 blocks
    const int blk = (L & 7) * 1024 + (L >> 3);        // bijective chunk map
    const int tok = blk * 2 + (threadIdx.x >> 7);
    const int e8  = (threadIdx.x & 127) * 8;
    const int t   = tok & (TSEQ - 1);

    const float rs0 = rsqrtf(ssq1[tok] * (1.0f / N1) + EPSV);
    const int tm = (t > 0) ? tok - 1 : tok;
    const int tp = (t < TSEQ - 1) ? tok + 1 : tok;
    const float rsm = (t > 0) ? rsqrtf(ssq1[tm] * (1.0f / N1) + EPSV) : 0.0f;
    const float rsp = (t < TSEQ - 1) ? rsqrtf(ssq1[tp] * (1.0f / N1) + EPSV) : 0.0f;

    bf16x8 xm = *(const bf16x8*)(z + (size_t)tm * N1 + e8);
    bf16x8 x0 = *(const bf16x8*)(z + (size_t)tok * N1 + e8);
    bf16x8 xp = *(const bf16x8*)(z + (size_t)tp * N1 + e8);
    bf16x8 vv = *(const bf16x8*)(z + (size_t)tok * N1 + EXP + e8);

    u16x8 ov;
#pragma unroll
    for (int p = 0; p < 8; ++p) {
        const int e = e8 + p;
        const float we  = inw[e];
        const float wvv = inw[EXP + e];
        const float w0 = cw[e * 3], w1 = cw[e * 3 + 1], w2 = cw[e * 3 + 2];
        float y = w0 * ((float)xm[p] * rsm * we)
                + w1 * ((float)x0[p] * rs0 * we)
                + w2 * ((float)xp[p] * rsp * we)
                + cb[e];
        float vn = (float)vv[p] * rs0 * wvv;
        ov[p] = f2bf(vn * y);
    }
    *(u16x8*)(g + (size_t)tok * EXP + e8) = ov;
}

// ---------------------------------------------------------------------------
// Final RMSNorm scale in place on fp32 output: out *= rsqrt(mean)*w.
// Thread-coarsened 4x: each thread handles 4 float4 of ONE token row
// (grid 4096 instead of 16384; pure-BW pass, fewer blocks to ramp).
__global__ __launch_bounds__(256) void k_outnorm(float* __restrict__ o,
                                                 const float* __restrict__ ssq2,
                                                 const float* __restrict__ onw) {
    const int idx = blockIdx.x * 256 + threadIdx.x;   // one 4-float4 strip
    const int tok = idx >> 6;                         // 64 strips per token
    const int d16 = (idx & 63) * 16;
    const float rs = rsqrtf(ssq2[tok] * (1.0f / DM) + EPSV);
    float4* po = (float4*)(o + (size_t)tok * DM + d16);
    const float4* pw = (const float4*)(onw + d16);
#pragma unroll
    for (int q = 0; q < 4; ++q) {
        float4 v = po[q];
        float4 w = pw[q];
        v.x *= rs * w.x; v.y *= rs * w.y; v.z *= rs * w.z; v.w *= rs * w.w;
        po[q] = v;
    }
}

// ---------------------------------------------------------------------------
extern "C" void kernel_launch(void* const* d_in, const int* in_sizes, int n_in,
                              void* d_out, int out_size, void* d_ws, size_t ws_size,
                              hipStream_t stream) {
    const float* u     = (const float*)d_in[0];
    const float* W_in  = (const float*)d_in[1];
    const float* b_in  = (const float*)d_in[2];
    const float* inw   = (const float*)d_in[3];
    const float* cw    = (const float*)d_in[4];
    const float* cb    = (const float*)d_in[5];
    const float* W_out = (const float*)d_in[6];
    const float* b_out = (const float*)d_in[7];
    const float* onw   = (const float*)d_in[8];
    float* out = (float*)d_out;

    char* ws = (char*)d_ws;
    unsigned short* u_bf    = (unsigned short*)ws; ws += (size_t)BT * DM * 2;     // 32 MB
    unsigned short* Win_bf  = (unsigned short*)ws; ws += (size_t)N1 * DM * 2;     //  4 MB
    unsigned short* Wout_bf = (unsigned short*)ws; ws += (size_t)DM * EXP * 2;    //  2 MB
    unsigned short* z_bf    = (unsigned short*)ws; ws += (size_t)BT * N1 * 2;     // 64 MB
    unsigned short* g_bf    = (unsigned short*)ws; ws += (size_t)BT * EXP * 2;    // 32 MB
    float* ssq1 = (float*)ws; ws += (size_t)BT * 4;
    float* ssq2 = (float*)ws; ws += (size_t)BT * 4;   // contiguous after ssq1

    const int n0 = BT * DM / 4, n1c = N1 * DM / 4, n2c = DM * EXP / 4;
    const int ntot = n0 + n1c + n2c + 2 * BT / 4;
    k_f2bf3<<<(ntot + 255) / 256, 256, 0, stream>>>(u, u_bf, n0,
                                                    W_in, Win_bf, n1c,
                                                    W_out, Wout_bf, n2c,
                                                    ssq1);

    k_gemm_in<<<(BT / 256) * (N1 / 128), 256, 0, stream>>>(u_bf, Win_bf, b_in, z_bf, ssq1);

    k_conv_gate<<<BT / 2, 256, 0, stream>>>(z_bf, ssq1, inw, cw, cb, g_bf);

    k_gemm_out<<<(BT / 256) * (DM / 128), 256, 0, stream>>>(g_bf, Wout_bf, b_out, out, ssq2);

    k_outnorm<<<BT / 4, 256, 0, stream>>>(out, ssq2, onw);

    (void)in_sizes; (void)n_in; (void)out_size; (void)ws_size;
}